// Round 11
// baseline (138.710 us; speedup 1.0000x reference)
//
#include <hip/hip_runtime.h>

typedef __bf16 bf16x8 __attribute__((ext_vector_type(8)));
typedef float floatx4 __attribute__((ext_vector_type(4)));
typedef float floatx16 __attribute__((ext_vector_type(16)));
typedef unsigned int uintx4 __attribute__((ext_vector_type(4)));

constexpr int Bc = 4, Hc = 8, Nc = 2048, Dc = 64;
constexpr int BQ = 128;      // q-rows per block
constexpr int WQ = 32;       // q-rows per wave
constexpr int TK = 64;       // keys per tile
constexpr int NT = Nc / TK;  // 32 tiles
constexpr int NT2 = NT / 2;  // 16 iterations (2 tiles/iter, dual stream)
constexpr float LOG2E = 1.44269504088896340736f;

// ws layout (~17.04 MB):
//   Ksw: [bh][jt] 8 KiB image, chunk g = key*8 + (kc ^ (key&7)) = K[key][kc*8..+7] bf16
//   Vsw: [bh][jt] 8 KiB image, chunk g = d*8   + (kc ^ (d&7))   = V^T[d][kc*8..+7] bf16
//   kkn: [bh][p] fp32 = -(sum K^2)*0.125*log2e, stored in 32x32 MFMA C-reg order:
//        p = jt*64 + kt*32 + hi*16 + r  <->  key = jt*64 + kt*32 + (r&3)+8*(r>>2)+4*hi
constexpr size_t KSW_OFF = 0;
constexpr size_t VSW_OFF = (size_t)32 * NT * 8192;   // 8 MiB
constexpr size_t KKN_OFF = VSW_OFF * 2;              // 16 MiB

// smem (66 KiB): sK [stream][buf] 4x8KiB, sV same, skk [buf][128] f32, sl [256] f32.
// Epilogue EXCH (8 slots x 4 KiB) reuses the sK region after last compute.
constexpr int SK_OFF  = 0;
constexpr int SV_OFF  = 32768;
constexpr int SKK_OFF = 65536;     // 2 bufs x 512 B
constexpr int SL_OFF  = 66560;     // 1 KiB
constexpr int SMEM_BYTES = 67584;

typedef __attribute__((address_space(1))) const unsigned int gu32;
typedef __attribute__((address_space(3))) unsigned int lu32;
__device__ __forceinline__ void dma16(const void* g, void* l) {
    __builtin_amdgcn_global_load_lds((gu32*)g, (lu32*)l, 16, 0, 0);
}
__device__ __forceinline__ void dma4(const void* g, void* l) {
    __builtin_amdgcn_global_load_lds((gu32*)g, (lu32*)l, 4, 0, 0);
}

__device__ __forceinline__ unsigned pk2(float lo, float hi) {
    unsigned short a = __builtin_bit_cast(unsigned short, (__bf16)lo);
    unsigned short b = __builtin_bit_cast(unsigned short, (__bf16)hi);
    return (unsigned)a | ((unsigned)b << 16);
}

// ---------------- prep: fully-coalesced image builder (kkn reordered) ----------------
__global__ __launch_bounds__(256) void prep_kernel(
    const float* __restrict__ Kg, const float* __restrict__ Vg, char* __restrict__ ws)
{
    __shared__ float sT[64 * 68];   // V tile [key][d], stride 68
    const int tid = threadIdx.x;
    const int jt = blockIdx.x, bh = blockIdx.y;

    __bf16* Ksw = (__bf16*)(ws + KSW_OFF) + ((size_t)bh * NT + jt) * 4096;
    __bf16* Vsw = (__bf16*)(ws + VSW_OFF) + ((size_t)bh * NT + jt) * 4096;
    float*  kkn = (float*)(ws + KKN_OFF) + (size_t)bh * Nc + jt * 64;
    const size_t tb = ((size_t)bh * Nc + jt * 64) * Dc;

#pragma unroll
    for (int cc = 0; cc < 2; ++cc) {
        const int g   = tid + cc * 256;
        const int key = g >> 3, kcx = g & 7;
        const int kc  = kcx ^ (key & 7);
        const float* src = Kg + tb + key * 64 + kc * 8;
        float4 a = *(const float4*)src;
        float4 b = *(const float4*)(src + 4);
        float ss = a.x*a.x + a.y*a.y + a.z*a.z + a.w*a.w
                 + b.x*b.x + b.y*b.y + b.z*b.z + b.w*b.w;
        ss += __shfl_xor(ss, 1);
        ss += __shfl_xor(ss, 2);
        ss += __shfl_xor(ss, 4);
        if (kcx == 0) {
            // reorder for 32x32 C-layout: key = kt*32 + (r&3)+8*(r>>2)+4*hi
            const int k5 = key & 31, kt = key >> 5;
            const int rlo = k5 & 3, hh = (k5 >> 2) & 1, rhi = k5 >> 3;
            kkn[kt * 32 + hh * 16 + rhi * 4 + rlo] = -(ss * 0.125f * LOG2E);
        }
        bf16x8 c8;
        c8[0]=(__bf16)a.x; c8[1]=(__bf16)a.y; c8[2]=(__bf16)a.z; c8[3]=(__bf16)a.w;
        c8[4]=(__bf16)b.x; c8[5]=(__bf16)b.y; c8[6]=(__bf16)b.z; c8[7]=(__bf16)b.w;
        *(bf16x8*)(Ksw + g * 8) = c8;
    }
    {
        const int js = tid >> 2, dc = (tid & 3) * 16;
        const float* vr = Vg + tb + js * 64 + dc;
        float* dst = &sT[js * 68 + dc];
        *(float4*)dst       = *(const float4*)vr;
        *(float4*)(dst + 4) = *(const float4*)(vr + 4);
        *(float4*)(dst + 8) = *(const float4*)(vr + 8);
        *(float4*)(dst + 12)= *(const float4*)(vr + 12);
    }
    __syncthreads();
#pragma unroll
    for (int cc = 0; cc < 2; ++cc) {
        const int g = tid + cc * 256;
        const int d = g >> 3, kcx = g & 7;
        const int kc = kcx ^ (d & 7);
        bf16x8 c8;
#pragma unroll
        for (int e = 0; e < 8; ++e) {
            const int ee = (e + kcx) & 7;
            c8[ee] = (__bf16)sT[(kc * 8 + ee) * 68 + d];
        }
        *(bf16x8*)(Vsw + g * 8) = c8;
    }
}

// ---------------- main fused attention: dual key-stream, 8 waves ----------------
// r11 = r9 (verified 56.5us: kk-via-LDS dma, XCD swizzle, permlane P-exchange,
// setprio) + l-sum folded into the MFMA pipe: one extra 32x32x16 MFMA per
// (kt,sub) with B = ones gives l[q] = sum_key P[q][key] directly in C-layout
// rows (lacc[r] is l for exactly the q-row this lane stores). Removes the 16
// fp32 VALU adds/iter and the epilogue shfl chain — moves work from the 45%-busy
// VALU pipe to the 25%-busy MFMA pipe. l now sums the SAME bf16-rounded P used
// in the PV numerator (consistent convex-combination normalization).
__global__ __launch_bounds__(512, 4) void attn_kernel(
    const float* __restrict__ Qg, const char* __restrict__ ws, float* __restrict__ Og)
{
    __shared__ __align__(16) char smem[SMEM_BYTES];

    const int tid  = threadIdx.x;
    const int wave = tid >> 6;        // 0..7
    const int grp  = wave >> 2;       // key stream: 0=even tiles, 1=odd tiles
    const int sw   = wave & 3;        // q sub-tile
    const int lane = tid & 63;
    const int r31  = lane & 31;
    const int hi   = lane >> 5;

    // XCD-aware swizzle: all 16 q-blocks of one bh land on the same XCD.
    const int lin  = blockIdx.x + (blockIdx.y << 4);   // 0..511
    const int xcd  = lin & 7, slot = lin >> 3;         // slot 0..63
    const int bh   = (xcd << 2) | (slot >> 4);         // 4 bh per XCD
    const int qt   = slot & 15;

    const char* Kimg = ws + KSW_OFF + (size_t)bh * NT * 8192;
    const char* Vimg = ws + VSW_OFF + (size_t)bh * NT * 8192;
    const float* kkp = (const float*)(ws + KKN_OFF) + (size_t)bh * Nc;

    const float qscale = 0.25f * LOG2E;
    const int i0 = qt * BQ + sw * WQ;

    // Q fragments (B-operand): qf[ks][j] = Q[i0+r31][ks*16+hi*8+j]*qscale
    bf16x8 qf[4];
    {
        const float* qrow = Qg + ((size_t)bh * Nc + i0 + r31) * Dc + hi * 8;
#pragma unroll
        for (int ks = 0; ks < 4; ++ks) {
            float4 a = *(const float4*)(qrow + ks * 16);
            float4 b = *(const float4*)(qrow + ks * 16 + 4);
            bf16x8 f;
            f[0] = (__bf16)(a.x * qscale); f[1] = (__bf16)(a.y * qscale);
            f[2] = (__bf16)(a.z * qscale); f[3] = (__bf16)(a.w * qscale);
            f[4] = (__bf16)(b.x * qscale); f[5] = (__bf16)(b.y * qscale);
            f[6] = (__bf16)(b.z * qscale); f[7] = (__bf16)(b.w * qscale);
            qf[ks] = f;
        }
    }

    // per-lane byte offsets into an 8 KiB image (shared by K and V reads);
    // row r31 (+kt/dt*32), chunk kc = ks*2+hi, swizzle ^ (row&7)
    int off4[4];
#pragma unroll
    for (int ks = 0; ks < 4; ++ks)
        off4[ks] = r31 * 128 + (((ks * 2 + hi) ^ (r31 & 7)) << 4);

    floatx16 oacc[2];
#pragma unroll
    for (int dt = 0; dt < 2; ++dt)
#pragma unroll
        for (int e = 0; e < 16; ++e) oacc[dt][e] = 0.f;
    floatx16 lacc;
#pragma unroll
    for (int e = 0; e < 16; ++e) lacc[e] = 0.f;

    bf16x8 vones;
#pragma unroll
    for (int j = 0; j < 8; ++j) vones[j] = (__bf16)1.0f;

    // stage tile-pair (2t, 2t+1): 16 KiB K + 16 KiB V + 512 B kk, all via dma
    auto stage = [&](int t, int nb) {
        const size_t tb = (size_t)t * 16384;
        const int off = tid * 16;     // 512 threads x 16B = 8 KiB per dma
        dma16(Kimg + tb + off,        smem + SK_OFF + nb * 8192 + off);
        dma16(Kimg + tb + 8192 + off, smem + SK_OFF + 16384 + nb * 8192 + off);
        dma16(Vimg + tb + off,        smem + SV_OFF + nb * 8192 + off);
        dma16(Vimg + tb + 8192 + off, smem + SV_OFF + 16384 + nb * 8192 + off);
        if (tid < 128)   // waves 0,1 fully active; 128 x 4B = both tiles' kk
            dma4(kkp + t * 128 + tid, smem + SKK_OFF + nb * 512 + tid * 4);
    };

    stage(0, 0);

    for (int t = 0; t < NT2; ++t) {
        const int b = t & 1;
        __syncthreads();                             // staged(t) visible
        if (t + 1 < NT2) stage(t + 1, b ^ 1);

        const char* kb = smem + SK_OFF + grp * 16384 + b * 8192;
        const char* vb = smem + SV_OFF + grp * 16384 + b * 8192;
        const float* skkb = (const float*)(smem + SKK_OFF + b * 512) + grp * 64 + hi * 16;

        // kk bias -> accumulator C-init via broadcast ds_read (lgkm only)
        floatx16 st[2];
#pragma unroll
        for (int kt = 0; kt < 2; ++kt)
#pragma unroll
            for (int gi = 0; gi < 4; ++gi) {
                floatx4 kv = *(const floatx4*)(skkb + kt * 32 + gi * 4);
                st[kt][gi * 4 + 0] = kv[0]; st[kt][gi * 4 + 1] = kv[1];
                st[kt][gi * 4 + 2] = kv[2]; st[kt][gi * 4 + 3] = kv[3];
            }

        // S^T(jt) = K.Q^T  (A = K frags from LDS, B = Q in regs)
        __builtin_amdgcn_s_setprio(1);
#pragma unroll
        for (int kt = 0; kt < 2; ++kt)
#pragma unroll
            for (int ks = 0; ks < 4; ++ks) {
                bf16x8 kf = *(const bf16x8*)(kb + kt * 4096 + off4[ks]);
                st[kt] = __builtin_amdgcn_mfma_f32_32x32x16_bf16(kf, qf[ks], st[kt], 0, 0, 0);
            }
        __builtin_amdgcn_s_setprio(0);

        // exp2 -> pack -> permlane exchange -> PV(jt) + l-MFMA, per 32-key half
#pragma unroll
        for (int kt = 0; kt < 2; ++kt) {
            float p[16];
#pragma unroll
            for (int r = 0; r < 16; ++r) p[r] = __builtin_amdgcn_exp2f(st[kt][r]);
            unsigned w[4][2];
#pragma unroll
            for (int g = 0; g < 4; ++g) {
                w[g][0] = pk2(p[4 * g + 0], p[4 * g + 1]);
                w[g][1] = pk2(p[4 * g + 2], p[4 * g + 3]);
            }
            __builtin_amdgcn_s_setprio(1);
#pragma unroll
            for (int sub = 0; sub < 2; ++sub) {
                unsigned a0 = w[2 * sub][0],     a1 = w[2 * sub][1];
                unsigned b0 = w[2 * sub + 1][0], b1 = w[2 * sub + 1][1];
                asm("v_permlane32_swap_b32 %0, %1" : "+v"(a0), "+v"(b0));
                asm("v_permlane32_swap_b32 %0, %1" : "+v"(a1), "+v"(b1));
                uintx4 u; u[0] = a0; u[1] = a1; u[2] = b0; u[3] = b1;
                bf16x8 pa = __builtin_bit_cast(bf16x8, u);
                const int ks = kt * 2 + sub;
#pragma unroll
                for (int dt = 0; dt < 2; ++dt) {
                    bf16x8 vf = *(const bf16x8*)(vb + dt * 4096 + off4[ks]);
                    oacc[dt] = __builtin_amdgcn_mfma_f32_32x32x16_bf16(pa, vf, oacc[dt], 0, 0, 0);
                }
                // l[q] += sum_key P[q][key] on the MFMA pipe (B = ones)
                lacc = __builtin_amdgcn_mfma_f32_32x32x16_bf16(pa, vones, lacc, 0, 0, 0);
            }
            __builtin_amdgcn_s_setprio(0);
        }
    }

    // ---- epilogue: cross-stream combine (pure adds; exp2-domain partials) ----
    // lacc rows are already per-q (col-duplicated): lane r31==0 of each hi-half
    // publishes this wave+stream's 16 l values.
    if (r31 == 0) {
#pragma unroll
        for (int r = 0; r < 16; ++r) {
            const int q = (r & 3) + 8 * (r >> 2) + 4 * hi;
            *(float*)(smem + SL_OFF + (grp * 128 + sw * 32 + q) * 4) = lacc[r];
        }
    }
    __syncthreads();   // all K/V reads done; sl visible; EXCH (sK region) now free

    // exchange the d-half this wave does NOT store (keeps dt==grp).
    // All oacc indices compile-time constant (wave-uniform branch on grp).
    {
        char* slot = smem + wave * 4096;
        if (grp == 0) {
#pragma unroll
            for (int r = 0; r < 16; ++r)
                *(float*)(slot + r * 256 + lane * 4) = oacc[1][r];
        } else {
#pragma unroll
            for (int r = 0; r < 16; ++r)
                *(float*)(slot + r * 256 + lane * 4) = oacc[0][r];
        }
    }
    __syncthreads();

    floatx16 osum;
    if (grp == 0) osum = oacc[0]; else osum = oacc[1];
    {
        const char* pslot = smem + (wave ^ 4) * 4096;
#pragma unroll
        for (int r = 0; r < 16; ++r)
            osum[r] += *(const float*)(pslot + r * 256 + lane * 4);
    }

    const float* slp = (const float*)(smem + SL_OFF);
    const int b_ = bh >> 3, hh = bh & 7;
#pragma unroll
    for (int g = 0; g < 4; ++g) {
        floatx4 la = *(const floatx4*)(slp + sw * 32 + 8 * g + 4 * hi);
        floatx4 lb = *(const floatx4*)(slp + 128 + sw * 32 + 8 * g + 4 * hi);
#pragma unroll
        for (int rlo = 0; rlo < 4; ++rlo) {
            const float inv = 1.f / (la[rlo] + lb[rlo]);
            const int i = i0 + 8 * g + 4 * hi + rlo;
            float* orow = Og + (((size_t)b_ * Nc + i) * Hc + hh) * Dc + grp * 32 + r31;
            orow[0] = osum[4 * g + rlo] * inv;
        }
    }
}

extern "C" void kernel_launch(void* const* d_in, const int* in_sizes, int n_in,
                              void* d_out, int out_size, void* d_ws, size_t ws_size,
                              hipStream_t stream) {
    const float* q = (const float*)d_in[0];
    const float* k = (const float*)d_in[1];
    const float* v = (const float*)d_in[2];
    float* out = (float*)d_out;
    char* ws = (char*)d_ws;   // ~17.04 MB
    prep_kernel<<<dim3(NT, Bc * Hc), 256, 0, stream>>>(k, v, ws);
    attn_kernel<<<dim3(Nc / BQ, Bc * Hc), 512, 0, stream>>>(q, ws, out);
}

// Round 12
// 132.663 us; speedup vs baseline: 1.0456x; 1.0456x over previous
//
#include <hip/hip_runtime.h>

typedef __bf16 bf16x2 __attribute__((ext_vector_type(2)));
typedef __bf16 bf16x8 __attribute__((ext_vector_type(8)));
typedef float floatx4 __attribute__((ext_vector_type(4)));
typedef float floatx16 __attribute__((ext_vector_type(16)));
typedef unsigned int uintx4 __attribute__((ext_vector_type(4)));

constexpr int Bc = 4, Hc = 8, Nc = 2048, Dc = 64;
constexpr int BQ = 128;      // q-rows per block
constexpr int WQ = 32;       // q-rows per wave
constexpr int TK = 64;       // keys per tile
constexpr int NT = Nc / TK;  // 32 tiles
constexpr int NT2 = NT / 2;  // 16 iterations (2 tiles/iter, dual stream)
constexpr float LOG2E = 1.44269504088896340736f;

// ws layout (~17.04 MB):
//   Ksw: [bh][jt] 8 KiB image, chunk g = key*8 + (kc ^ (key&7)) = K[key][kc*8..+7] bf16
//   Vsw: [bh][jt] 8 KiB image, chunk g = d*8   + (kc ^ (d&7))   = V^T[d][kc*8..+7] bf16
//   kkn: [bh][p] fp32 = -(sum K^2)*0.125*log2e, stored in 32x32 MFMA C-reg order:
//        p = jt*64 + kt*32 + hi*16 + r  <->  key = jt*64 + kt*32 + (r&3)+8*(r>>2)+4*hi
constexpr size_t KSW_OFF = 0;
constexpr size_t VSW_OFF = (size_t)32 * NT * 8192;   // 8 MiB
constexpr size_t KKN_OFF = VSW_OFF * 2;              // 16 MiB

// smem (66 KiB): sK [stream][buf] 4x8KiB, sV same, skk [buf][128] f32, sl [256] f32.
// Epilogue EXCH (8 slots x 4 KiB) reuses the sK region after last compute.
constexpr int SK_OFF  = 0;
constexpr int SV_OFF  = 32768;
constexpr int SKK_OFF = 65536;     // 2 bufs x 512 B
constexpr int SL_OFF  = 66560;     // 1 KiB
constexpr int SMEM_BYTES = 67584;

typedef __attribute__((address_space(1))) const unsigned int gu32;
typedef __attribute__((address_space(3))) unsigned int lu32;
__device__ __forceinline__ void dma16(const void* g, void* l) {
    __builtin_amdgcn_global_load_lds((gu32*)g, (lu32*)l, 16, 0, 0);
}
__device__ __forceinline__ void dma4(const void* g, void* l) {
    __builtin_amdgcn_global_load_lds((gu32*)g, (lu32*)l, 4, 0, 0);
}

// vector-form bf16 pair pack -> encourages a single v_cvt_pk_bf16_f32
__device__ __forceinline__ unsigned pk2(float lo, float hi) {
    bf16x2 t;
    t[0] = (__bf16)lo;
    t[1] = (__bf16)hi;
    return __builtin_bit_cast(unsigned, t);
}

// ---------------- prep: fully-coalesced image builder (kkn reordered) ----------------
__global__ __launch_bounds__(256) void prep_kernel(
    const float* __restrict__ Kg, const float* __restrict__ Vg, char* __restrict__ ws)
{
    __shared__ float sT[64 * 68];   // V tile [key][d], stride 68
    const int tid = threadIdx.x;
    const int jt = blockIdx.x, bh = blockIdx.y;

    __bf16* Ksw = (__bf16*)(ws + KSW_OFF) + ((size_t)bh * NT + jt) * 4096;
    __bf16* Vsw = (__bf16*)(ws + VSW_OFF) + ((size_t)bh * NT + jt) * 4096;
    float*  kkn = (float*)(ws + KKN_OFF) + (size_t)bh * Nc + jt * 64;
    const size_t tb = ((size_t)bh * Nc + jt * 64) * Dc;

#pragma unroll
    for (int cc = 0; cc < 2; ++cc) {
        const int g   = tid + cc * 256;
        const int key = g >> 3, kcx = g & 7;
        const int kc  = kcx ^ (key & 7);
        const float* src = Kg + tb + key * 64 + kc * 8;
        float4 a = *(const float4*)src;
        float4 b = *(const float4*)(src + 4);
        float ss = a.x*a.x + a.y*a.y + a.z*a.z + a.w*a.w
                 + b.x*b.x + b.y*b.y + b.z*b.z + b.w*b.w;
        ss += __shfl_xor(ss, 1);
        ss += __shfl_xor(ss, 2);
        ss += __shfl_xor(ss, 4);
        if (kcx == 0) {
            // reorder for 32x32 C-layout: key = kt*32 + (r&3)+8*(r>>2)+4*hi
            const int k5 = key & 31, kt = key >> 5;
            const int rlo = k5 & 3, hh = (k5 >> 2) & 1, rhi = k5 >> 3;
            kkn[kt * 32 + hh * 16 + rhi * 4 + rlo] = -(ss * 0.125f * LOG2E);
        }
        bf16x8 c8;
        c8[0]=(__bf16)a.x; c8[1]=(__bf16)a.y; c8[2]=(__bf16)a.z; c8[3]=(__bf16)a.w;
        c8[4]=(__bf16)b.x; c8[5]=(__bf16)b.y; c8[6]=(__bf16)b.z; c8[7]=(__bf16)b.w;
        *(bf16x8*)(Ksw + g * 8) = c8;
    }
    {
        const int js = tid >> 2, dc = (tid & 3) * 16;
        const float* vr = Vg + tb + js * 64 + dc;
        float* dst = &sT[js * 68 + dc];
        *(float4*)dst       = *(const float4*)vr;
        *(float4*)(dst + 4) = *(const float4*)(vr + 4);
        *(float4*)(dst + 8) = *(const float4*)(vr + 8);
        *(float4*)(dst + 12)= *(const float4*)(vr + 12);
    }
    __syncthreads();
#pragma unroll
    for (int cc = 0; cc < 2; ++cc) {
        const int g = tid + cc * 256;
        const int d = g >> 3, kcx = g & 7;
        const int kc = kcx ^ (d & 7);
        bf16x8 c8;
#pragma unroll
        for (int e = 0; e < 8; ++e) {
            const int ee = (e + kcx) & 7;
            c8[ee] = (__bf16)sT[(kc * 8 + ee) * 68 + d];
        }
        *(bf16x8*)(Vsw + g * 8) = c8;
    }
}

// ---------------- main fused attention: dual key-stream, 8 waves ----------------
// r12 = r9 (verified best, 56.5us: kk-via-LDS dma, XCD swizzle, permlane
// P-exchange, setprio) + issue-cycle shaves (r10/r11 established the kernel is
// SIMD issue-port bound — moving work between pipes is neutral; only reducing
// instruction count helps):
//  (1) pk2 as bf16x2 vector init -> v_cvt_pk_bf16_f32 (48 insts -> 16 per iter
//      if the compiler wasn't fusing).
//  (2) main loop unrolled x2 so buffer index b is a literal; all K/V/skk
//      ds_reads become {loop-invariant base reg} + {compile-time imm offset}
//      (K: b*8192+kt*4096; V: 32768+b*8192+dt*4096; skk: b*512+kt*128+gi*16)
//      -> zero per-iteration address arithmetic.
//  (3) l-sum back on VALU (r11's l-MFMA was issue-neutral; r9 form is simpler).
__global__ __launch_bounds__(512, 4) void attn_kernel(
    const float* __restrict__ Qg, const char* __restrict__ ws, float* __restrict__ Og)
{
    __shared__ __align__(16) char smem[SMEM_BYTES];

    const int tid  = threadIdx.x;
    const int wave = tid >> 6;        // 0..7
    const int grp  = wave >> 2;       // key stream: 0=even tiles, 1=odd tiles
    const int sw   = wave & 3;        // q sub-tile
    const int lane = tid & 63;
    const int r31  = lane & 31;
    const int hi   = lane >> 5;

    // XCD-aware swizzle: all 16 q-blocks of one bh land on the same XCD.
    const int lin  = blockIdx.x + (blockIdx.y << 4);   // 0..511
    const int xcd  = lin & 7, slot = lin >> 3;         // slot 0..63
    const int bh   = (xcd << 2) | (slot >> 4);         // 4 bh per XCD
    const int qt   = slot & 15;

    const char* Kimg = ws + KSW_OFF + (size_t)bh * NT * 8192;
    const char* Vimg = ws + VSW_OFF + (size_t)bh * NT * 8192;
    const float* kkp = (const float*)(ws + KKN_OFF) + (size_t)bh * Nc;

    const float qscale = 0.25f * LOG2E;
    const int i0 = qt * BQ + sw * WQ;

    // Q fragments (B-operand): qf[ks][j] = Q[i0+r31][ks*16+hi*8+j]*qscale
    bf16x8 qf[4];
    {
        const float* qrow = Qg + ((size_t)bh * Nc + i0 + r31) * Dc + hi * 8;
#pragma unroll
        for (int ks = 0; ks < 4; ++ks) {
            float4 a = *(const float4*)(qrow + ks * 16);
            float4 b = *(const float4*)(qrow + ks * 16 + 4);
            bf16x8 f;
            f[0] = (__bf16)(a.x * qscale); f[1] = (__bf16)(a.y * qscale);
            f[2] = (__bf16)(a.z * qscale); f[3] = (__bf16)(a.w * qscale);
            f[4] = (__bf16)(b.x * qscale); f[5] = (__bf16)(b.y * qscale);
            f[6] = (__bf16)(b.z * qscale); f[7] = (__bf16)(b.w * qscale);
            qf[ks] = f;
        }
    }

    // Loop-invariant LDS read bases. Element (row r31 + kt/dt*32, chunk kc=ks*2+hi,
    // XOR-swizzled by row&7). Every ds_read in the loop = ka[ks] + literal imm.
    int ka[4];
#pragma unroll
    for (int ks = 0; ks < 4; ++ks)
        ka[ks] = grp * 16384 + r31 * 128 + (((ks * 2 + hi) ^ (r31 & 7)) << 4);
    const int skbase = SKK_OFF + (grp * 64 + hi * 16) * 4;

    floatx16 oacc[2];
#pragma unroll
    for (int dt = 0; dt < 2; ++dt)
#pragma unroll
        for (int e = 0; e < 16; ++e) oacc[dt][e] = 0.f;
    float lpr0 = 0.f, lpr1 = 0.f;

    // stage tile-pair (2t, 2t+1): 16 KiB K + 16 KiB V + 512 B kk, all via dma
    auto stage = [&](int t, int nb) {
        const size_t tb = (size_t)t * 16384;
        const int off = tid * 16;     // 512 threads x 16B = 8 KiB per dma
        dma16(Kimg + tb + off,        smem + SK_OFF + nb * 8192 + off);
        dma16(Kimg + tb + 8192 + off, smem + SK_OFF + 16384 + nb * 8192 + off);
        dma16(Vimg + tb + off,        smem + SV_OFF + nb * 8192 + off);
        dma16(Vimg + tb + 8192 + off, smem + SV_OFF + 16384 + nb * 8192 + off);
        if (tid < 128)   // waves 0,1 fully active; 128 x 4B = both tiles' kk
            dma4(kkp + t * 128 + tid, smem + SKK_OFF + nb * 512 + tid * 4);
    };

    // one iteration; called with LITERAL b so all LDS offsets fold to immediates
    auto iter = [&](int t, int b) {
        __syncthreads();                             // staged(t) visible
        if (t + 1 < NT2) stage(t + 1, b ^ 1);

        // kk bias -> accumulator C-init via broadcast ds_read (lgkm only)
        floatx16 st[2];
#pragma unroll
        for (int kt = 0; kt < 2; ++kt)
#pragma unroll
            for (int gi = 0; gi < 4; ++gi) {
                floatx4 kv = *(const floatx4*)(smem + skbase + b * 512 + kt * 128 + gi * 16);
                st[kt][gi * 4 + 0] = kv[0]; st[kt][gi * 4 + 1] = kv[1];
                st[kt][gi * 4 + 2] = kv[2]; st[kt][gi * 4 + 3] = kv[3];
            }

        // S^T = K.Q^T  (A = K frags from LDS, B = Q in regs)
        __builtin_amdgcn_s_setprio(1);
#pragma unroll
        for (int kt = 0; kt < 2; ++kt)
#pragma unroll
            for (int ks = 0; ks < 4; ++ks) {
                bf16x8 kf = *(const bf16x8*)(smem + ka[ks] + (b * 8192 + kt * 4096));
                st[kt] = __builtin_amdgcn_mfma_f32_32x32x16_bf16(kf, qf[ks], st[kt], 0, 0, 0);
            }
        __builtin_amdgcn_s_setprio(0);

        // exp2 -> pack -> permlane exchange -> PV, per 32-key half
#pragma unroll
        for (int kt = 0; kt < 2; ++kt) {
            float p[16];
#pragma unroll
            for (int r = 0; r < 16; ++r) p[r] = __builtin_amdgcn_exp2f(st[kt][r]);
#pragma unroll
            for (int r = 0; r < 16; r += 2) { lpr0 += p[r]; lpr1 += p[r + 1]; }
            unsigned w[4][2];
#pragma unroll
            for (int g = 0; g < 4; ++g) {
                w[g][0] = pk2(p[4 * g + 0], p[4 * g + 1]);
                w[g][1] = pk2(p[4 * g + 2], p[4 * g + 3]);
            }
            __builtin_amdgcn_s_setprio(1);
#pragma unroll
            for (int sub = 0; sub < 2; ++sub) {
                unsigned a0 = w[2 * sub][0],     a1 = w[2 * sub][1];
                unsigned b0 = w[2 * sub + 1][0], b1 = w[2 * sub + 1][1];
                asm("v_permlane32_swap_b32 %0, %1" : "+v"(a0), "+v"(b0));
                asm("v_permlane32_swap_b32 %0, %1" : "+v"(a1), "+v"(b1));
                uintx4 u; u[0] = a0; u[1] = a1; u[2] = b0; u[3] = b1;
                bf16x8 pa = __builtin_bit_cast(bf16x8, u);
                const int ks = kt * 2 + sub;
#pragma unroll
                for (int dt = 0; dt < 2; ++dt) {
                    bf16x8 vf = *(const bf16x8*)(smem + ka[ks] + (32768 + b * 8192 + dt * 4096));
                    oacc[dt] = __builtin_amdgcn_mfma_f32_32x32x16_bf16(pa, vf, oacc[dt], 0, 0, 0);
                }
            }
            __builtin_amdgcn_s_setprio(0);
        }
    };

    stage(0, 0);

    for (int tt = 0; tt < NT2; tt += 2) {   // 2x unroll -> b is a literal
        iter(tt, 0);
        iter(tt + 1, 1);
    }

    // ---- epilogue: cross-stream combine (pure adds; exp2-domain partials) ----
    {
        float lpr = lpr0 + lpr1;
        float l = lpr + __shfl_xor(lpr, 32);
        if (!hi) *(float*)(smem + SL_OFF + (grp * 128 + sw * 32 + r31) * 4) = l;
    }
    __syncthreads();   // all K/V reads done; sl visible; EXCH (sK region) now free

    // exchange the d-half this wave does NOT store (keeps dt==grp).
    // All oacc indices compile-time constant (wave-uniform branch on grp).
    {
        char* slot = smem + wave * 4096;
        if (grp == 0) {
#pragma unroll
            for (int r = 0; r < 16; ++r)
                *(float*)(slot + r * 256 + lane * 4) = oacc[1][r];
        } else {
#pragma unroll
            for (int r = 0; r < 16; ++r)
                *(float*)(slot + r * 256 + lane * 4) = oacc[0][r];
        }
    }
    __syncthreads();

    floatx16 osum;
    if (grp == 0) osum = oacc[0]; else osum = oacc[1];
    {
        const char* pslot = smem + (wave ^ 4) * 4096;
#pragma unroll
        for (int r = 0; r < 16; ++r)
            osum[r] += *(const float*)(pslot + r * 256 + lane * 4);
    }

    const float* slp = (const float*)(smem + SL_OFF);
    const int b_ = bh >> 3, hh = bh & 7;
#pragma unroll
    for (int g = 0; g < 4; ++g) {
        floatx4 la = *(const floatx4*)(slp + sw * 32 + 8 * g + 4 * hi);
        floatx4 lb = *(const floatx4*)(slp + 128 + sw * 32 + 8 * g + 4 * hi);
#pragma unroll
        for (int rlo = 0; rlo < 4; ++rlo) {
            const float inv = 1.f / (la[rlo] + lb[rlo]);
            const int i = i0 + 8 * g + 4 * hi + rlo;
            float* orow = Og + (((size_t)b_ * Nc + i) * Hc + hh) * Dc + grp * 32 + r31;
            orow[0] = osum[4 * g + rlo] * inv;
        }
    }
}

extern "C" void kernel_launch(void* const* d_in, const int* in_sizes, int n_in,
                              void* d_out, int out_size, void* d_ws, size_t ws_size,
                              hipStream_t stream) {
    const float* q = (const float*)d_in[0];
    const float* k = (const float*)d_in[1];
    const float* v = (const float*)d_in[2];
    float* out = (float*)d_out;
    char* ws = (char*)d_ws;   // ~17.04 MB
    prep_kernel<<<dim3(NT, Bc * Hc), 256, 0, stream>>>(k, v, ws);
    attn_kernel<<<dim3(Nc / BQ, Bc * Hc), 512, 0, stream>>>(q, ws, out);
}

// Round 13
// 132.609 us; speedup vs baseline: 1.0460x; 1.0004x over previous
//
#include <hip/hip_runtime.h>

typedef __bf16 bf16x2 __attribute__((ext_vector_type(2)));
typedef __bf16 bf16x8 __attribute__((ext_vector_type(8)));
typedef float floatx4 __attribute__((ext_vector_type(4)));
typedef float floatx16 __attribute__((ext_vector_type(16)));
typedef unsigned int uintx4 __attribute__((ext_vector_type(4)));

constexpr int Bc = 4, Hc = 8, Nc = 2048, Dc = 64;
constexpr int BQ = 128;      // q-rows per block
constexpr int WQ = 32;       // q-rows per wave
constexpr int TK = 64;       // keys per tile
constexpr int NT = Nc / TK;  // 32 tiles
constexpr int NT2 = NT / 2;  // 16 iterations (2 tiles/iter, dual stream)
constexpr float LOG2E = 1.44269504088896340736f;

// ws layout (~17.04 MB):
//   Ksw: [bh][jt] 8 KiB image, CHUNK-MAJOR: chunk c = kc*64 + key at byte c*16,
//        content K[key][kc*8..+7] bf16. A frag read (fixed kc, 32 rows) is then
//        512 B CONTIGUOUS in LDS -> conflict-free (r12 had an inherent 4-way
//        conflict: 128 B rows all start at bank 0 and lanes with equal r31&7
//        collide; no 16B-aligned row stride can fix it -> layout change).
//   Vsw: same, row = d: chunk c = kc*64 + d, content V^T[d][kc*8..+7].
//   kkn: [bh][p] fp32 = -(sum K^2)*0.125*log2e, stored in 32x32 MFMA C-reg order:
//        p = jt*64 + kt*32 + hi*16 + r  <->  key = jt*64 + kt*32 + (r&3)+8*(r>>2)+4*hi
constexpr size_t KSW_OFF = 0;
constexpr size_t VSW_OFF = (size_t)32 * NT * 8192;   // 8 MiB
constexpr size_t KKN_OFF = VSW_OFF * 2;              // 16 MiB

// smem (66 KiB): sK [stream][buf] 4x8KiB, sV same, skk [buf][128] f32, sl [256] f32.
// Epilogue EXCH (8 slots x 4 KiB) reuses the sK region after last compute.
constexpr int SK_OFF  = 0;
constexpr int SV_OFF  = 32768;
constexpr int SKK_OFF = 65536;     // 2 bufs x 512 B
constexpr int SL_OFF  = 66560;     // 1 KiB
constexpr int SMEM_BYTES = 67584;

typedef __attribute__((address_space(1))) const unsigned int gu32;
typedef __attribute__((address_space(3))) unsigned int lu32;
__device__ __forceinline__ void dma16(const void* g, void* l) {
    __builtin_amdgcn_global_load_lds((gu32*)g, (lu32*)l, 16, 0, 0);
}
__device__ __forceinline__ void dma4(const void* g, void* l) {
    __builtin_amdgcn_global_load_lds((gu32*)g, (lu32*)l, 4, 0, 0);
}

// vector-form bf16 pair pack -> single v_cvt_pk_bf16_f32
__device__ __forceinline__ unsigned pk2(float lo, float hi) {
    bf16x2 t;
    t[0] = (__bf16)lo;
    t[1] = (__bf16)hi;
    return __builtin_bit_cast(unsigned, t);
}

// ---------------- prep: chunk-major image builder (kkn reordered) ----------------
__global__ __launch_bounds__(256) void prep_kernel(
    const float* __restrict__ Kg, const float* __restrict__ Vg, char* __restrict__ ws)
{
    __shared__ float sT[64 * 68];   // V tile [key][d], stride 68
    const int tid = threadIdx.x;
    const int jt = blockIdx.x, bh = blockIdx.y;

    __bf16* Ksw = (__bf16*)(ws + KSW_OFF) + ((size_t)bh * NT + jt) * 4096;
    __bf16* Vsw = (__bf16*)(ws + VSW_OFF) + ((size_t)bh * NT + jt) * 4096;
    float*  kkn = (float*)(ws + KKN_OFF) + (size_t)bh * Nc + jt * 64;
    const size_t tb = ((size_t)bh * Nc + jt * 64) * Dc;

#pragma unroll
    for (int cc = 0; cc < 2; ++cc) {
        const int g   = tid + cc * 256;
        const int key = g >> 3, kc = g & 7;
        const float* src = Kg + tb + key * 64 + kc * 8;
        float4 a = *(const float4*)src;
        float4 b = *(const float4*)(src + 4);
        float ss = a.x*a.x + a.y*a.y + a.z*a.z + a.w*a.w
                 + b.x*b.x + b.y*b.y + b.z*b.z + b.w*b.w;
        ss += __shfl_xor(ss, 1);
        ss += __shfl_xor(ss, 2);
        ss += __shfl_xor(ss, 4);
        if (kc == 0) {
            // reorder for 32x32 C-layout: key = kt*32 + (r&3)+8*(r>>2)+4*hi
            const int k5 = key & 31, kt = key >> 5;
            const int rlo = k5 & 3, hh = (k5 >> 2) & 1, rhi = k5 >> 3;
            kkn[kt * 32 + hh * 16 + rhi * 4 + rlo] = -(ss * 0.125f * LOG2E);
        }
        bf16x8 c8;
        c8[0]=(__bf16)a.x; c8[1]=(__bf16)a.y; c8[2]=(__bf16)a.z; c8[3]=(__bf16)a.w;
        c8[4]=(__bf16)b.x; c8[5]=(__bf16)b.y; c8[6]=(__bf16)b.z; c8[7]=(__bf16)b.w;
        *(bf16x8*)(Ksw + (kc * 64 + key) * 8) = c8;   // chunk-major
    }
    {
        const int js = tid >> 2, dc = (tid & 3) * 16;
        const float* vr = Vg + tb + js * 64 + dc;
        float* dst = &sT[js * 68 + dc];
        *(float4*)dst       = *(const float4*)vr;
        *(float4*)(dst + 4) = *(const float4*)(vr + 4);
        *(float4*)(dst + 8) = *(const float4*)(vr + 8);
        *(float4*)(dst + 12)= *(const float4*)(vr + 12);
    }
    __syncthreads();
#pragma unroll
    for (int cc = 0; cc < 2; ++cc) {
        const int g = tid + cc * 256;
        const int d = g >> 3, kc = g & 7;
        bf16x8 c8;
#pragma unroll
        for (int e = 0; e < 8; ++e) {
            const int ee = (e + kc) & 7;           // rotated iteration order (sT banks)
            c8[ee] = (__bf16)sT[(kc * 8 + ee) * 68 + d];
        }
        *(bf16x8*)(Vsw + (kc * 64 + d) * 8) = c8;  // chunk-major
    }
}

// ---------------- main fused attention: dual key-stream, 8 waves ----------------
// r13 = r12 (verified best, 52.2us: kk-via-LDS dma, XCD swizzle, permlane
// P-exchange, setprio, cvt_pk, literal-offset ds_reads) + chunk-major K/V
// images: every K/V frag read is 512 B contiguous per half-wave ->
// bank-conflict-free (r12: 4-way inherent, 4.19M conflict cycles/dispatch).
__global__ __launch_bounds__(512, 4) void attn_kernel(
    const float* __restrict__ Qg, const char* __restrict__ ws, float* __restrict__ Og)
{
    __shared__ __align__(16) char smem[SMEM_BYTES];

    const int tid  = threadIdx.x;
    const int wave = tid >> 6;        // 0..7
    const int grp  = wave >> 2;       // key stream: 0=even tiles, 1=odd tiles
    const int sw   = wave & 3;        // q sub-tile
    const int lane = tid & 63;
    const int r31  = lane & 31;
    const int hi   = lane >> 5;

    // XCD-aware swizzle: all 16 q-blocks of one bh land on the same XCD.
    const int lin  = blockIdx.x + (blockIdx.y << 4);   // 0..511
    const int xcd  = lin & 7, slot = lin >> 3;         // slot 0..63
    const int bh   = (xcd << 2) | (slot >> 4);         // 4 bh per XCD
    const int qt   = slot & 15;

    const char* Kimg = ws + KSW_OFF + (size_t)bh * NT * 8192;
    const char* Vimg = ws + VSW_OFF + (size_t)bh * NT * 8192;
    const float* kkp = (const float*)(ws + KKN_OFF) + (size_t)bh * Nc;

    const float qscale = 0.25f * LOG2E;
    const int i0 = qt * BQ + sw * WQ;

    // Q fragments (B-operand): qf[ks][j] = Q[i0+r31][ks*16+hi*8+j]*qscale
    bf16x8 qf[4];
    {
        const float* qrow = Qg + ((size_t)bh * Nc + i0 + r31) * Dc + hi * 8;
#pragma unroll
        for (int ks = 0; ks < 4; ++ks) {
            float4 a = *(const float4*)(qrow + ks * 16);
            float4 b = *(const float4*)(qrow + ks * 16 + 4);
            bf16x8 f;
            f[0] = (__bf16)(a.x * qscale); f[1] = (__bf16)(a.y * qscale);
            f[2] = (__bf16)(a.z * qscale); f[3] = (__bf16)(a.w * qscale);
            f[4] = (__bf16)(b.x * qscale); f[5] = (__bf16)(b.y * qscale);
            f[6] = (__bf16)(b.z * qscale); f[7] = (__bf16)(b.w * qscale);
            qf[ks] = f;
        }
    }

    // Loop-invariant LDS read bases (chunk-major image):
    //   frag (kc = ks*2+hi, row = r31 + {kt,dt}*32) at kc*1024 + row*16.
    // Every ds_read = ka[ks] + literal imm (K: b*8192 + kt*512; V: 32768 + b*8192 + dt*512).
    int ka[4];
#pragma unroll
    for (int ks = 0; ks < 4; ++ks)
        ka[ks] = grp * 16384 + ((ks * 2 + hi) << 10) + r31 * 16;
    const int skbase = SKK_OFF + (grp * 64 + hi * 16) * 4;

    floatx16 oacc[2];
#pragma unroll
    for (int dt = 0; dt < 2; ++dt)
#pragma unroll
        for (int e = 0; e < 16; ++e) oacc[dt][e] = 0.f;
    float lpr0 = 0.f, lpr1 = 0.f;

    // stage tile-pair (2t, 2t+1): 16 KiB K + 16 KiB V + 512 B kk, all via dma
    auto stage = [&](int t, int nb) {
        const size_t tb = (size_t)t * 16384;
        const int off = tid * 16;     // 512 threads x 16B = 8 KiB per dma
        dma16(Kimg + tb + off,        smem + SK_OFF + nb * 8192 + off);
        dma16(Kimg + tb + 8192 + off, smem + SK_OFF + 16384 + nb * 8192 + off);
        dma16(Vimg + tb + off,        smem + SV_OFF + nb * 8192 + off);
        dma16(Vimg + tb + 8192 + off, smem + SV_OFF + 16384 + nb * 8192 + off);
        if (tid < 128)   // waves 0,1 fully active; 128 x 4B = both tiles' kk
            dma4(kkp + t * 128 + tid, smem + SKK_OFF + nb * 512 + tid * 4);
    };

    // one iteration; called with LITERAL b so all LDS offsets fold to immediates
    auto iter = [&](int t, int b) {
        __syncthreads();                             // staged(t) visible
        if (t + 1 < NT2) stage(t + 1, b ^ 1);

        // kk bias -> accumulator C-init via broadcast ds_read (lgkm only)
        floatx16 st[2];
#pragma unroll
        for (int kt = 0; kt < 2; ++kt)
#pragma unroll
            for (int gi = 0; gi < 4; ++gi) {
                floatx4 kv = *(const floatx4*)(smem + skbase + b * 512 + kt * 128 + gi * 16);
                st[kt][gi * 4 + 0] = kv[0]; st[kt][gi * 4 + 1] = kv[1];
                st[kt][gi * 4 + 2] = kv[2]; st[kt][gi * 4 + 3] = kv[3];
            }

        // S^T = K.Q^T  (A = K frags from LDS, B = Q in regs)
        __builtin_amdgcn_s_setprio(1);
#pragma unroll
        for (int kt = 0; kt < 2; ++kt)
#pragma unroll
            for (int ks = 0; ks < 4; ++ks) {
                bf16x8 kf = *(const bf16x8*)(smem + ka[ks] + (b * 8192 + kt * 512));
                st[kt] = __builtin_amdgcn_mfma_f32_32x32x16_bf16(kf, qf[ks], st[kt], 0, 0, 0);
            }
        __builtin_amdgcn_s_setprio(0);

        // exp2 -> pack -> permlane exchange -> PV, per 32-key half
#pragma unroll
        for (int kt = 0; kt < 2; ++kt) {
            float p[16];
#pragma unroll
            for (int r = 0; r < 16; ++r) p[r] = __builtin_amdgcn_exp2f(st[kt][r]);
#pragma unroll
            for (int r = 0; r < 16; r += 2) { lpr0 += p[r]; lpr1 += p[r + 1]; }
            unsigned w[4][2];
#pragma unroll
            for (int g = 0; g < 4; ++g) {
                w[g][0] = pk2(p[4 * g + 0], p[4 * g + 1]);
                w[g][1] = pk2(p[4 * g + 2], p[4 * g + 3]);
            }
            __builtin_amdgcn_s_setprio(1);
#pragma unroll
            for (int sub = 0; sub < 2; ++sub) {
                unsigned a0 = w[2 * sub][0],     a1 = w[2 * sub][1];
                unsigned b0 = w[2 * sub + 1][0], b1 = w[2 * sub + 1][1];
                asm("v_permlane32_swap_b32 %0, %1" : "+v"(a0), "+v"(b0));
                asm("v_permlane32_swap_b32 %0, %1" : "+v"(a1), "+v"(b1));
                uintx4 u; u[0] = a0; u[1] = a1; u[2] = b0; u[3] = b1;
                bf16x8 pa = __builtin_bit_cast(bf16x8, u);
                const int ks = kt * 2 + sub;
#pragma unroll
                for (int dt = 0; dt < 2; ++dt) {
                    bf16x8 vf = *(const bf16x8*)(smem + ka[ks] + (32768 + b * 8192 + dt * 512));
                    oacc[dt] = __builtin_amdgcn_mfma_f32_32x32x16_bf16(pa, vf, oacc[dt], 0, 0, 0);
                }
            }
            __builtin_amdgcn_s_setprio(0);
        }
    };

    stage(0, 0);

    for (int tt = 0; tt < NT2; tt += 2) {   // 2x unroll -> b is a literal
        iter(tt, 0);
        iter(tt + 1, 1);
    }

    // ---- epilogue: cross-stream combine (pure adds; exp2-domain partials) ----
    {
        float lpr = lpr0 + lpr1;
        float l = lpr + __shfl_xor(lpr, 32);
        if (!hi) *(float*)(smem + SL_OFF + (grp * 128 + sw * 32 + r31) * 4) = l;
    }
    __syncthreads();   // all K/V reads done; sl visible; EXCH (sK region) now free

    // exchange the d-half this wave does NOT store (keeps dt==grp).
    // All oacc indices compile-time constant (wave-uniform branch on grp).
    {
        char* slot = smem + wave * 4096;
        if (grp == 0) {
#pragma unroll
            for (int r = 0; r < 16; ++r)
                *(float*)(slot + r * 256 + lane * 4) = oacc[1][r];
        } else {
#pragma unroll
            for (int r = 0; r < 16; ++r)
                *(float*)(slot + r * 256 + lane * 4) = oacc[0][r];
        }
    }
    __syncthreads();

    floatx16 osum;
    if (grp == 0) osum = oacc[0]; else osum = oacc[1];
    {
        const char* pslot = smem + (wave ^ 4) * 4096;
#pragma unroll
        for (int r = 0; r < 16; ++r)
            osum[r] += *(const float*)(pslot + r * 256 + lane * 4);
    }

    const float* slp = (const float*)(smem + SL_OFF);
    const int b_ = bh >> 3, hh = bh & 7;
#pragma unroll
    for (int g = 0; g < 4; ++g) {
        floatx4 la = *(const floatx4*)(slp + sw * 32 + 8 * g + 4 * hi);
        floatx4 lb = *(const floatx4*)(slp + 128 + sw * 32 + 8 * g + 4 * hi);
#pragma unroll
        for (int rlo = 0; rlo < 4; ++rlo) {
            const float inv = 1.f / (la[rlo] + lb[rlo]);
            const int i = i0 + 8 * g + 4 * hi + rlo;
            float* orow = Og + (((size_t)b_ * Nc + i) * Hc + hh) * Dc + grp * 32 + r31;
            orow[0] = osum[4 * g + rlo] * inv;
        }
    }
}

extern "C" void kernel_launch(void* const* d_in, const int* in_sizes, int n_in,
                              void* d_out, int out_size, void* d_ws, size_t ws_size,
                              hipStream_t stream) {
    const float* q = (const float*)d_in[0];
    const float* k = (const float*)d_in[1];
    const float* v = (const float*)d_in[2];
    float* out = (float*)d_out;
    char* ws = (char*)d_ws;   // ~17.04 MB
    prep_kernel<<<dim3(NT, Bc * Hc), 256, 0, stream>>>(k, v, ws);
    attn_kernel<<<dim3(Nc / BQ, Bc * Hc), 512, 0, stream>>>(q, ws, out);
}